// Round 3
// baseline (672.135 us; speedup 1.0000x reference)
//
#include <hip/hip_runtime.h>

// out[b] = sum_i x[b,i] * |W[i]| * fc1_w[i] + fc1_b ; B=32, N = T*P = 4e6.
// Each (block.x, group) computes s = |W|*fc1_w once and reuses it across 8
// batch rows -> minimal HBM traffic (~544 MB => ~86 us floor at 6.3 TB/s).
// This rev: 32 B per stream per thread (two consecutive float4s) for deeper
// MLP and 2 KB-contiguous per-wave bursts per stream.
#define BATCH 32
#define NELEM 4000000
#define N4 (NELEM / 4)     // 1,000,000 float4 per batch row
#define BLK 256
#define BPG 8              // batch rows per group
#define GROUPS (BATCH / BPG)
#define NBLK 512           // blocks per group -> 2048 blocks, 8192 waves total

__global__ __launch_bounds__(BLK)
void stage1_kernel(const float4* __restrict__ x,   // [BATCH][N4]
                   const float4* __restrict__ W,   // [N4]
                   const float4* __restrict__ F,   // [N4]
                   float* __restrict__ partials) { // [BATCH][NBLK]
    const int g  = blockIdx.y;
    const int bx = blockIdx.x;
    const float4* __restrict__ xg = x + (size_t)g * BPG * N4;

    float acc[BPG];
    #pragma unroll
    for (int r = 0; r < BPG; ++r) acc[r] = 0.0f;

    const int stride = 2 * NBLK * BLK;              // in float4 units
    for (int i = (bx * BLK + threadIdx.x) * 2; i < N4; i += stride) {
        // N4 is even and i is even -> i+1 is always in bounds.
        float4 w0 = W[i],     w1 = W[i + 1];
        float4 f0 = F[i],     f1 = F[i + 1];
        float4 s0, s1;
        s0.x = fabsf(w0.x) * f0.x;  s0.y = fabsf(w0.y) * f0.y;
        s0.z = fabsf(w0.z) * f0.z;  s0.w = fabsf(w0.w) * f0.w;
        s1.x = fabsf(w1.x) * f1.x;  s1.y = fabsf(w1.y) * f1.y;
        s1.z = fabsf(w1.z) * f1.z;  s1.w = fabsf(w1.w) * f1.w;
        #pragma unroll
        for (int r = 0; r < BPG; ++r) {
            const float4* __restrict__ xp = xg + (size_t)r * N4 + i;
            float4 x0 = xp[0];
            float4 x1 = xp[1];
            acc[r] += x0.x * s0.x + x0.y * s0.y + x0.z * s0.z + x0.w * s0.w
                    + x1.x * s1.x + x1.y * s1.y + x1.z * s1.z + x1.w * s1.w;
        }
    }

    #pragma unroll
    for (int r = 0; r < BPG; ++r) {
        #pragma unroll
        for (int off = 32; off > 0; off >>= 1)
            acc[r] += __shfl_down(acc[r], off, 64);
    }

    __shared__ float lds[BLK / 64][BPG];
    const int lane = threadIdx.x & 63;
    const int wv   = threadIdx.x >> 6;
    if (lane == 0) {
        #pragma unroll
        for (int r = 0; r < BPG; ++r) lds[wv][r] = acc[r];
    }
    __syncthreads();

    if (threadIdx.x < BPG) {
        const int r = threadIdx.x;
        float t = lds[0][r] + lds[1][r] + lds[2][r] + lds[3][r];
        partials[(size_t)(g * BPG + r) * NBLK + bx] = t;
    }
}

__global__ __launch_bounds__(64)
void stage2_kernel(const float* __restrict__ partials, // [BATCH][NBLK]
                   const float* __restrict__ fc1_b,
                   float* __restrict__ out) {          // [BATCH]
    const int b    = blockIdx.x;
    const int lane = threadIdx.x;
    float t = 0.0f;
    #pragma unroll
    for (int k = lane; k < NBLK; k += 64) t += partials[(size_t)b * NBLK + k];
    #pragma unroll
    for (int off = 32; off > 0; off >>= 1) t += __shfl_down(t, off, 64);
    if (lane == 0) out[b] = t + fc1_b[0];
}

extern "C" void kernel_launch(void* const* d_in, const int* in_sizes, int n_in,
                              void* d_out, int out_size, void* d_ws, size_t ws_size,
                              hipStream_t stream) {
    const float* x     = (const float*)d_in[0];  // [B, T, P]
    const float* W     = (const float*)d_in[1];  // [T, P]
    const float* fc1_w = (const float*)d_in[2];  // [1, T*P]
    const float* fc1_b = (const float*)d_in[3];  // [1]
    float* out      = (float*)d_out;             // [B, 1]
    float* partials = (float*)d_ws;              // BATCH*NBLK floats (64 KB)

    dim3 grid(NBLK, GROUPS);
    stage1_kernel<<<grid, BLK, 0, stream>>>(
        (const float4*)x, (const float4*)W, (const float4*)fc1_w, partials);
    stage2_kernel<<<BATCH, 64, 0, stream>>>(partials, fc1_b, out);
}